// Round 11
// baseline (254.494 us; speedup 1.0000x reference)
//
#include <hip/hip_runtime.h>
#include <stdint.h>

#define N_ 8192
#define D_ 1024
// logit = dot(imn,capn)/T; fp8 operands pre-scaled by 16 -> acc = 256*dot
// (MX scales set to E8M0 1.0 -> identical numerics to plain fp8 MFMA)
#define EPILOGUE_SCALE (10.0f / 256.0f)
#define ENC_SCALE 16.0f
#define CHUNK 524288  // bytes of one K-chunk (64 K-bytes x 8192 rows): 256 T32-tiles x 2048B

typedef float f32x4 __attribute__((ext_vector_type(4)));
typedef float f32x16 __attribute__((ext_vector_type(16)));
typedef int i32x4 __attribute__((ext_vector_type(4)));
typedef int i32x8 __attribute__((ext_vector_type(8)));

// async global->LDS, 16B per lane, LDS dest = wave-uniform base + lane*16
#define GLD16(gsrc, ldst)                                                    \
  __builtin_amdgcn_global_load_lds(                                          \
      (const __attribute__((address_space(1))) unsigned int*)(gsrc),         \
      (__attribute__((address_space(3))) unsigned int*)(ldst), 16, 0, 0)

// R4 fragment layout (32x32x64 f8f6f4 family pattern), both operands, 8MB:
//   byte addr = c*CHUNK + T32*2048 + p*1024 + l*16 + o   (c:K-chunk of 64,
//   T32: 32-row tile, p: K-16B-half, l: lane, o in [0,16))
//   holds row = T32*32 + (l&31), k = c*64 + (l>>5)*32 + p*16 + o.

// Kernel 1 [R10 version + cnt zero]: registers-only, zero-sync normalize.
// Lane j loads row bytes [64j,64j+64); output granule j is exactly lane j's
// registers (j = 4c+2g+p => 16j = 64c+32g+16p). No LDS, no barrier.
__global__ __launch_bounds__(256) void normalize_k(
    const float* __restrict__ im, const float* __restrict__ cap,
    unsigned int* __restrict__ imn, unsigned int* __restrict__ capn,
    float* __restrict__ diag, float* __restrict__ sums /* rowsum|colsum */,
    unsigned int* __restrict__ cnt) {
  const int b = blockIdx.x;
  const int t = threadIdx.x;
  // zero rowsum|colsum: 16 blocks x 256 threads x float4 = 16384 floats
  if (b < 16) ((float4*)sums)[b * 256 + t] = (float4){0.f, 0.f, 0.f, 0.f};
  if (b == 0 && t == 0) *cnt = 0u;  // reset last-block counter each replay

  const int j = t & 63;               // lane
  const int row = b * 4 + (t >> 6);   // one wave per row
  const float4* __restrict__ aR = (const float4*)(im + (size_t)row * D_);
  const float4* __restrict__ bR = (const float4*)(cap + (size_t)row * D_);

  // lane j owns float4s 4j..4j+3 = row floats [16j, 16j+16)
  float4 a0 = aR[j * 4], a1 = aR[j * 4 + 1], a2 = aR[j * 4 + 2], a3 = aR[j * 4 + 3];
  float4 b0 = bR[j * 4], b1 = bR[j * 4 + 1], b2 = bR[j * 4 + 2], b3 = bR[j * 4 + 3];

  float ssa = a0.x * a0.x + a0.y * a0.y + a0.z * a0.z + a0.w * a0.w
            + a1.x * a1.x + a1.y * a1.y + a1.z * a1.z + a1.w * a1.w
            + a2.x * a2.x + a2.y * a2.y + a2.z * a2.z + a2.w * a2.w
            + a3.x * a3.x + a3.y * a3.y + a3.z * a3.z + a3.w * a3.w;
  float ssb = b0.x * b0.x + b0.y * b0.y + b0.z * b0.z + b0.w * b0.w
            + b1.x * b1.x + b1.y * b1.y + b1.z * b1.z + b1.w * b1.w
            + b2.x * b2.x + b2.y * b2.y + b2.z * b2.z + b2.w * b2.w
            + b3.x * b3.x + b3.y * b3.y + b3.z * b3.z + b3.w * b3.w;
  float dt  = a0.x * b0.x + a0.y * b0.y + a0.z * b0.z + a0.w * b0.w
            + a1.x * b1.x + a1.y * b1.y + a1.z * b1.z + a1.w * b1.w
            + a2.x * b2.x + a2.y * b2.y + a2.z * b2.z + a2.w * b2.w
            + a3.x * b3.x + a3.y * b3.y + a3.z * b3.z + a3.w * b3.w;
#pragma unroll
  for (int o = 1; o < 64; o <<= 1) {  // full-wave butterfly (row = 1 wave)
    ssa += __shfl_xor(ssa, o, 64);
    ssb += __shfl_xor(ssb, o, 64);
    dt  += __shfl_xor(dt, o, 64);
  }
  const float ra = rsqrtf(ssa), rb = rsqrtf(ssb);
  if (j == 0) diag[row] = dt * ra * rb * 10.0f;
  const float sa = ra * ENC_SCALE, sb = rb * ENC_SCALE;

#define PK(v, s, lo) \
  { lo = __builtin_amdgcn_cvt_pk_fp8_f32(v.x * s, v.y * s, 0, false); \
    lo = __builtin_amdgcn_cvt_pk_fp8_f32(v.z * s, v.w * s, lo, true); }
  int pa0, pa1, pa2, pa3, pb0, pb1, pb2, pb3;
  PK(a0, sa, pa0) PK(a1, sa, pa1) PK(a2, sa, pa2) PK(a3, sa, pa3)
  PK(b0, sb, pb0) PK(b1, sb, pb1) PK(b2, sb, pb2) PK(b3, sb, pb3)
#undef PK
  uint4 va = {(unsigned)pa0, (unsigned)pa1, (unsigned)pa2, (unsigned)pa3};
  uint4 vb = {(unsigned)pb0, (unsigned)pb1, (unsigned)pb2, (unsigned)pb3};

  // dest: granule j -> c=j>>2, g=(j>>1)&1, p=j&1
  {
    const int c = j >> 2, g = (j >> 1) & 1, p = j & 1;
    const size_t d = (size_t)c * CHUNK + (size_t)(row >> 5) * 2048
                   + (size_t)(p << 10) + (size_t)((g << 5) + (row & 31)) * 16;
    *(uint4*)((unsigned char*)imn + d) = va;
    *(uint4*)((unsigned char*)capn + d) = vb;
  }
}

// Kernel 2 [R19]: persistent blocks + fused finalize on the frozen R8 inner
// loop. grid 512 = exactly 2 blocks/CU all-resident; each block owns 4
// adjacent col-tiles of one rowT (A panel fetched 1x instead of 4x; 3 of 4
// prologue refills + all round-transition bubbles removed). Flat 64-step
// K-stream (tile tt = kk>>4, kc = kk&15) over the SAME ring-3/vmcnt(3)/
// 1-barrier discipline; per-tile epilogue in-loop (uniform branch); vmcnt(3)
// stays correct with epilogue atomics in the FIFO (the 3 newest outstanding
// can only be the next tile's loads -> compute tile always retired;
// boundary stalls on atomic drain are conservative-only). Finalize fused
// via last-block counter + agent-scope atomic loads (XCD-coherent).
__global__ __launch_bounds__(512, 4) void gemm_lse_k(
    const unsigned char* __restrict__ A,   // fragment-layout imn
    const unsigned char* __restrict__ B,   // fragment-layout capn
    float* __restrict__ rowsum, float* __restrict__ colsum,
    const float* __restrict__ diag, float* __restrict__ out,
    unsigned int* __restrict__ cnt) {
  __shared__ unsigned char lds[3][24576];  // ring-3: [A 16KB | B 8KB] each
  __shared__ unsigned int lastFlag;
  __shared__ float red[2][8];
  const int t = threadIdx.x;
  const int w = t >> 6, l = t & 63;
  const int l16 = l * 16;

  // XCD swizzle on 512 blocks: 64/XCD; 4 rowTs x 16 colGs per XCD.
  const int bid = blockIdx.x;                      // 0..511
  const int nid = (bid & 7) * 64 + (bid >> 3);     // bijective (512%8==0)
  const int rowT = ((nid >> 6) << 2) + (nid & 3);  // 0..31 (256-row panels)
  const int colG = (nid >> 2) & 15;                // 0..15 (4 col-tiles each)

  const size_t baseA = (size_t)rowT * 16384;   // 8 T32 x 2048B per chunk
  const size_t baseB = (size_t)colG * 32768;   // 4 tiles x 4 T32 x 2048B

  // staging: 24KB/step = 24 x 1KB; wave w owns 3 (mixed A/B roles).
  // B-role pointers advance by tt*8192 per col-tile; A-role fixed.
  const unsigned char* srcc[3];
  int bstr[3], ldsOff[3];
#pragma unroll
  for (int c = 0; c < 3; ++c) {
    const int o = w * 3072 + c * 1024;
    ldsOff[c] = o;
    if (o < 16384) { srcc[c] = A + baseA + o + l16;           bstr[c] = 0; }
    else           { srcc[c] = B + baseB + (o - 16384) + l16; bstr[c] = 8192; }
  }

#define STAGE(kk, buf)                                                       \
  {                                                                          \
    const int kc_ = (kk) & 15, tt_ = (kk) >> 4;                              \
    const size_t kofs = (size_t)kc_ * CHUNK;                                 \
    GLD16(srcc[0] + kofs + (size_t)tt_ * bstr[0], &lds[buf][ldsOff[0]]);     \
    GLD16(srcc[1] + kofs + (size_t)tt_ * bstr[1], &lds[buf][ldsOff[1]]);     \
    GLD16(srcc[2] + kofs + (size_t)tt_ * bstr[2], &lds[buf][ldsOff[2]]);     \
  }

  const int wr = w >> 1, wc = w & 1;  // 4M x 2N waves, 64x64 each (2x2 T32)

  f32x16 acc[2][2];
#pragma unroll
  for (int m = 0; m < 2; ++m)
#pragma unroll
    for (int n = 0; n < 2; ++n)
#pragma unroll
      for (int r = 0; r < 16; ++r) acc[m][n][r] = 0.f;

#define COMPUTE(buf)                                                         \
  {                                                                          \
    const unsigned char* Lc = &lds[buf][0];                                  \
    i32x8 a_[2], b_[2];                                                      \
    _Pragma("unroll")                                                        \
    for (int m = 0; m < 2; ++m) {                                            \
      i32x4 lo = *(const i32x4*)(Lc + (wr * 2 + m) * 2048 + l16);            \
      i32x4 hi = *(const i32x4*)(Lc + (wr * 2 + m) * 2048 + 1024 + l16);     \
      a_[m] = __builtin_shufflevector(lo, hi, 0, 1, 2, 3, 4, 5, 6, 7);       \
    }                                                                        \
    _Pragma("unroll")                                                        \
    for (int n = 0; n < 2; ++n) {                                            \
      i32x4 lo = *(const i32x4*)(Lc + 16384 + (wc * 2 + n) * 2048 + l16);    \
      i32x4 hi = *(const i32x4*)(Lc + 16384 + (wc * 2 + n) * 2048 + 1024 + l16); \
      b_[n] = __builtin_shufflevector(lo, hi, 0, 1, 2, 3, 4, 5, 6, 7);       \
    }                                                                        \
    __builtin_amdgcn_s_setprio(1);                                           \
    _Pragma("unroll")                                                        \
    for (int m = 0; m < 2; ++m)                                              \
      _Pragma("unroll")                                                      \
      for (int n = 0; n < 2; ++n)                                            \
        acc[m][n] = __builtin_amdgcn_mfma_scale_f32_32x32x64_f8f6f4(         \
            a_[m], b_[n], acc[m][n], 0, 0, 0, 0x7F7F7F7F, 0, 0x7F7F7F7F);    \
    __builtin_amdgcn_s_setprio(0);                                           \
  }

  // epilogue for col-tile tt_: exp + row/col partial sums, then re-zero acc.
  // 32x32 C/D layout: col = lane&31, row = (reg&3)+8*(reg>>2)+4*(lane>>5)
  // [measured m74/m101]
#define EPILOGUE(tt_)                                                        \
  {                                                                          \
    _Pragma("unroll")                                                        \
    for (int m = 0; m < 2; ++m)                                              \
      _Pragma("unroll")                                                      \
      for (int n = 0; n < 2; ++n)                                            \
        _Pragma("unroll")                                                    \
        for (int r = 0; r < 16; ++r)                                         \
          acc[m][n][r] = __expf(acc[m][n][r] * EPILOGUE_SCALE);              \
    const int rowBase = rowT * 256 + wr * 64;                                \
    const int colBase = (colG * 4 + (tt_)) * 128 + wc * 64;                  \
    _Pragma("unroll")                                                        \
    for (int m = 0; m < 2; ++m) {                                            \
      f32x16 s = acc[m][0] + acc[m][1];                                      \
      _Pragma("unroll")                                                      \
      for (int r = 0; r < 16; ++r) {                                         \
        float v = s[r];                                                      \
        v += __shfl_xor(v, 1, 64);                                           \
        v += __shfl_xor(v, 2, 64);                                           \
        v += __shfl_xor(v, 4, 64);                                           \
        v += __shfl_xor(v, 8, 64);                                           \
        v += __shfl_xor(v, 16, 64);                                          \
        if ((l & 31) == 0)                                                   \
          atomicAdd(&rowsum[rowBase + m * 32 + (r & 3) + 8 * (r >> 2)        \
                            + 4 * (l >> 5)], v);                             \
      }                                                                      \
    }                                                                        \
    _Pragma("unroll")                                                        \
    for (int n = 0; n < 2; ++n) {                                            \
      float v = 0.f;                                                         \
      _Pragma("unroll")                                                      \
      for (int r = 0; r < 16; ++r) v += acc[0][n][r] + acc[1][n][r];         \
      v += __shfl_xor(v, 32, 64);                                            \
      if (l < 32) atomicAdd(&colsum[colBase + n * 32 + l], v);               \
    }                                                                        \
    _Pragma("unroll")                                                        \
    for (int m = 0; m < 2; ++m)                                              \
      _Pragma("unroll")                                                      \
      for (int n = 0; n < 2; ++n)                                            \
        _Pragma("unroll")                                                    \
        for (int r = 0; r < 16; ++r) acc[m][n][r] = 0.f;                     \
  }

  // prologue: steps 0,1 in flight (6 loads/wave)
  STAGE(0, 0)
  STAGE(1, 1)

  // flat 64-step loop (R8 discipline verbatim; epilogue at tile boundaries)
  int tt = 0;
#pragma unroll 1
  for (int kk = 0; kk < 62; ++kk) {
    asm volatile("s_waitcnt vmcnt(3)" ::: "memory");
    __builtin_amdgcn_s_barrier();
    STAGE(kk + 2, (kk + 2) % 3)
    COMPUTE(kk % 3)
    if ((kk & 15) == 15) { EPILOGUE(tt) ++tt; }
  }
  // tail: steps 62 (buf 2), 63 (buf 0) of tile 3
  asm volatile("s_waitcnt vmcnt(3)" ::: "memory");
  __builtin_amdgcn_s_barrier();
  COMPUTE(2)
  asm volatile("s_waitcnt vmcnt(0)" ::: "memory");
  __builtin_amdgcn_s_barrier();
  COMPUTE(0)
  EPILOGUE(3)
#undef EPILOGUE
#undef COMPUTE
#undef STAGE

  // fused finalize: last block to arrive reduces rowsum/colsum/diag -> out.
  __threadfence();  // release: our atomics visible device-wide before inc
  if (t == 0) lastFlag = (atomicAdd(cnt, 1u) == 511u) ? 1u : 0u;
  __syncthreads();
  if (lastFlag) {
    __threadfence();  // acquire side
    float lse = 0.f, dg = 0.f;
    for (int i = t; i < N_; i += 512) {
      const float rs = __hip_atomic_load(&rowsum[i], __ATOMIC_RELAXED,
                                         __HIP_MEMORY_SCOPE_AGENT);
      const float cs = __hip_atomic_load(&colsum[i], __ATOMIC_RELAXED,
                                         __HIP_MEMORY_SCOPE_AGENT);
      const float dd = __hip_atomic_load(&diag[i], __ATOMIC_RELAXED,
                                         __HIP_MEMORY_SCOPE_AGENT);
      lse += __logf(rs) + __logf(cs);
      dg += dd;
    }
#pragma unroll
    for (int o = 32; o > 0; o >>= 1) {
      lse += __shfl_down(lse, o, 64);
      dg  += __shfl_down(dg, o, 64);
    }
    if (l == 0) { red[0][w] = lse; red[1][w] = dg; }
    __syncthreads();
    if (t == 0) {
      lse = red[0][0] + red[0][1] + red[0][2] + red[0][3]
          + red[0][4] + red[0][5] + red[0][6] + red[0][7];
      dg  = red[1][0] + red[1][1] + red[1][2] + red[1][3]
          + red[1][4] + red[1][5] + red[1][6] + red[1][7];
      out[0] = 0.5f * lse / (float)N_ - dg / (float)N_;
    }
  }
}

extern "C" void kernel_launch(void* const* d_in, const int* in_sizes, int n_in,
                              void* d_out, int out_size, void* d_ws, size_t ws_size,
                              hipStream_t stream) {
  const float* im = (const float*)d_in[0];
  const float* cap = (const float*)d_in[1];
  float* out = (float*)d_out;
  char* ws = (char*)d_ws;
  unsigned char* imn = (unsigned char*)ws;                 // 8 MB fp8 (fragment layout)
  unsigned char* capn = imn + (size_t)N_ * D_;             // 8 MB fp8 (fragment layout)
  float* rowsum = (float*)(ws + 2 * (size_t)N_ * D_);
  float* colsum = rowsum + N_;
  float* diag = colsum + N_;
  unsigned int* cnt = (unsigned int*)(diag + N_);

  normalize_k<<<2048, 256, 0, stream>>>(im, cap, (unsigned int*)imn,
                                        (unsigned int*)capn, diag, rowsum, cnt);
  gemm_lse_k<<<512, 512, 0, stream>>>(imn, capn, rowsum, colsum, diag, out, cnt);
}

// Round 12
// 189.070 us; speedup vs baseline: 1.3460x; 1.3460x over previous
//
#include <hip/hip_runtime.h>
#include <stdint.h>

#define N_ 8192
#define D_ 1024
// logit = dot(imn,capn)/T; fp8 operands pre-scaled by 16 -> acc = 256*dot
// (MX scales set to E8M0 1.0 -> identical numerics to plain fp8 MFMA)
#define EPILOGUE_SCALE (10.0f / 256.0f)
#define ENC_SCALE 16.0f
#define CHUNK 524288  // bytes of one K-chunk (64 K-bytes x 8192 rows): 256 T32-tiles x 2048B

typedef float f32x4 __attribute__((ext_vector_type(4)));
typedef float f32x16 __attribute__((ext_vector_type(16)));
typedef int i32x4 __attribute__((ext_vector_type(4)));
typedef int i32x8 __attribute__((ext_vector_type(8)));

// async global->LDS, 16B per lane, LDS dest = wave-uniform base + lane*16
#define GLD16(gsrc, ldst)                                                    \
  __builtin_amdgcn_global_load_lds(                                          \
      (const __attribute__((address_space(1))) unsigned int*)(gsrc),         \
      (__attribute__((address_space(3))) unsigned int*)(ldst), 16, 0, 0)

// R4 fragment layout (32x32x64 f8f6f4 family pattern), both operands, 8MB:
//   byte addr = c*CHUNK + T32*2048 + p*1024 + l*16 + o   (c:K-chunk of 64,
//   T32: 32-row tile, p: K-16B-half, l: lane, o in [0,16))
//   holds row = T32*32 + (l&31), k = c*64 + (l>>5)*32 + p*16 + o.

// ============================================================================
// R12: byte-restore of the session optimum (R7, 190.3 us measured).
// R11's persistent+fused gemm regressed to 254.5 (epilogue atomics poisoned
// the vmcnt FIFO: every vmcnt(3) drained the atomic backlog; MfmaUtil 17%).
// Session bracket: gemm pinned 92.4-93.9 across 4 sane schedule variants
// (2-bar/ring-2 = 1-bar/ring-3+setprio; B-direct and persistent regress);
// normalize flat across 5 designs incl. zero-sync registers-only; fusion
// negative. This file = empirical argmin of the 12-round search.
// ============================================================================

// Kernel 1 [R7 version]: 16-row blocks aligned to the layout's 32-row tile
// unit; store phase writes 4x 256B contiguous runs per instruction. 512
// blocks x 256 thr (4 waves x 4 sequential rows), LDS 33KB -> 4 blocks/CU.
__global__ __launch_bounds__(256, 4) void normalize_k(
    const float* __restrict__ im, const float* __restrict__ cap,
    unsigned int* __restrict__ imn, unsigned int* __restrict__ capn,
    float* __restrict__ diag, float* __restrict__ sums /* rowsum|colsum */) {
  __shared__ unsigned int ldsA[16 * 260];  // stride 260: 16B-aligned rows
  __shared__ unsigned int ldsB[16 * 260];
  const int b = blockIdx.x;  // 512 blocks x 16 rows
  const int t = threadIdx.x;
  // zero rowsum|colsum: 16 blocks x 256 threads x float4 = 16384 floats
  if (b < 16) ((float4*)sums)[b * 256 + t] = (float4){0.f, 0.f, 0.f, 0.f};

  const int w = t >> 6, j = t & 63;  // wave w handles rows w*4..w*4+3; lane j
#pragma unroll 1
  for (int i = 0; i < 4; ++i) {
    const int r = w * 4 + i;        // block-local row 0..15
    const int row = b * 16 + r;
    const float4* __restrict__ aR = (const float4*)(im + (size_t)row * D_);
    const float4* __restrict__ bR = (const float4*)(cap + (size_t)row * D_);

    float4 a0 = aR[j], a1 = aR[j + 64], a2 = aR[j + 128], a3 = aR[j + 192];
    float4 b0 = bR[j], b1 = bR[j + 64], b2 = bR[j + 128], b3 = bR[j + 192];

    float ssa = a0.x * a0.x + a0.y * a0.y + a0.z * a0.z + a0.w * a0.w
              + a1.x * a1.x + a1.y * a1.y + a1.z * a1.z + a1.w * a1.w
              + a2.x * a2.x + a2.y * a2.y + a2.z * a2.z + a2.w * a2.w
              + a3.x * a3.x + a3.y * a3.y + a3.z * a3.z + a3.w * a3.w;
    float ssb = b0.x * b0.x + b0.y * b0.y + b0.z * b0.z + b0.w * b0.w
              + b1.x * b1.x + b1.y * b1.y + b1.z * b1.z + b1.w * b1.w
              + b2.x * b2.x + b2.y * b2.y + b2.z * b2.z + b2.w * b2.w
              + b3.x * b3.x + b3.y * b3.y + b3.z * b3.z + b3.w * b3.w;
    float dt  = a0.x * b0.x + a0.y * b0.y + a0.z * b0.z + a0.w * b0.w
              + a1.x * b1.x + a1.y * b1.y + a1.z * b1.z + a1.w * b1.w
              + a2.x * b2.x + a2.y * b2.y + a2.z * b2.z + a2.w * b2.w
              + a3.x * b3.x + a3.y * b3.y + a3.z * b3.z + a3.w * b3.w;
#pragma unroll
    for (int o = 1; o < 64; o <<= 1) {  // full-wave butterfly (row = 1 wave)
      ssa += __shfl_xor(ssa, o, 64);
      ssb += __shfl_xor(ssb, o, 64);
      dt  += __shfl_xor(dt, o, 64);
    }
    const float ra = rsqrtf(ssa), rb = rsqrtf(ssb);
    if (j == 0) diag[row] = dt * ra * rb * 10.0f;
    const float sa = ra * ENC_SCALE, sb = rb * ENC_SCALE;

#define CVT_ST(av, bv, ofs)                                                  \
  {                                                                          \
    int pa_ = __builtin_amdgcn_cvt_pk_fp8_f32(av.x * sa, av.y * sa, 0, false); \
    pa_ = __builtin_amdgcn_cvt_pk_fp8_f32(av.z * sa, av.w * sa, pa_, true);  \
    int pb_ = __builtin_amdgcn_cvt_pk_fp8_f32(bv.x * sb, bv.y * sb, 0, false); \
    pb_ = __builtin_amdgcn_cvt_pk_fp8_f32(bv.z * sb, bv.w * sb, pb_, true);  \
    ldsA[r * 260 + j + (ofs)] = (unsigned int)pa_;                           \
    ldsB[r * 260 + j + (ofs)] = (unsigned int)pb_;                           \
  }
    CVT_ST(a0, b0, 0)
    CVT_ST(a1, b1, 64)
    CVT_ST(a2, b2, 128)
    CVT_ST(a3, b3, 192)
#undef CVT_ST
  }
  __syncthreads();

  // store phase: thread (c = t>>4, i = t&15) emits row i's 64 bytes of
  // K-chunk c as 4 granules (g,p). LDS dword k holds row-bytes [4k,4k+4):
  // granule (c,g,p) = dwords [c*16+g*8+p*4, +4). Dest lane = g*32 +
  // (b&1)*16 + i -> per store instr a wave writes 4x 256B contiguous runs.
  {
    const int c = t >> 4, i2 = t & 15;
    const size_t base = (size_t)c * CHUNK + (size_t)(b >> 1) * 2048;
    const int rhalf = (b & 1) * 16;
#pragma unroll
    for (int g = 0; g < 2; ++g)
#pragma unroll
      for (int p = 0; p < 2; ++p) {
        const int src = i2 * 260 + c * 16 + g * 8 + p * 4;
        const uint4 va = *(const uint4*)&ldsA[src];
        const uint4 vb = *(const uint4*)&ldsB[src];
        const size_t d = base + (size_t)(p << 10)
                       + (size_t)((g * 32 + rhalf + i2) * 16);
        *(uint4*)((unsigned char*)imn + d) = va;
        *(uint4*)((unsigned char*)capn + d) = vb;
      }
  }
}

// Kernel 2 [R4 verbatim — 92.6us proven optimum of the family]: MX-scaled
// fp8 GEMM on ring-2/vmcnt(3)/2-barrier skeleton. 256x128 block tile, 8
// waves (4Mx2N) of 64x64 (2x2 of 32x32 -> acc 64 VGPR). BK=64 = 1
// K-chunk/iter, 16 iters. LDS 2x24KB -> 2 blocks/CU.
__global__ __launch_bounds__(512, 4) void gemm_lse_k(
    const unsigned char* __restrict__ A,   // fragment-layout imn
    const unsigned char* __restrict__ B,   // fragment-layout capn
    float* __restrict__ rowsum, float* __restrict__ colsum) {
  __shared__ unsigned char lds[2][24576];  // ring-2: [A 16KB | B 8KB] each
  const int t = threadIdx.x;
  const int w = t >> 6, l = t & 63;
  const int l16 = l * 16;

  // XCD/L2 swizzle: 256-block chunk per XCD.
  const int bid = blockIdx.x + (blockIdx.y << 5);     // 0..2047
  const int nid = (bid & 7) * 256 + (bid >> 3);       // bijective (2048%8==0)
  const int rowT = ((nid >> 8) << 2) + (nid & 3);     // 0..31
  const int colT = (nid >> 2) & 63;                   // 0..63

  const size_t baseA = (size_t)rowT * 16384;  // 8 T32-tiles x 2048B per chunk
  const size_t baseB = (size_t)colT * 8192;   // 4 T32-tiles x 2048B per chunk

  // staging: 24KB/tile = 24 x 1KB chunks; wave w owns 3 (mixed A/B).
  const unsigned char* src[3];
  int ldsOff[3];
#pragma unroll
  for (int c = 0; c < 3; ++c) {
    const int o = w * 3072 + c * 1024;
    ldsOff[c] = o;
    src[c] = (o < 16384) ? (A + baseA + o + l16)
                         : (B + baseB + (o - 16384) + l16);
  }

#define STAGE(kc, buf)                                                       \
  {                                                                          \
    const size_t kofs = (size_t)(kc) * CHUNK;                                \
    GLD16(src[0] + kofs, &lds[buf][ldsOff[0]]);                              \
    GLD16(src[1] + kofs, &lds[buf][ldsOff[1]]);                              \
    GLD16(src[2] + kofs, &lds[buf][ldsOff[2]]);                              \
  }

  const int wr = w >> 1, wc = w & 1;  // 4M x 2N waves, 64x64 each (2x2 T32)

  f32x16 acc[2][2];
#pragma unroll
  for (int m = 0; m < 2; ++m)
#pragma unroll
    for (int n = 0; n < 2; ++n)
#pragma unroll
      for (int r = 0; r < 16; ++r) acc[m][n][r] = 0.f;

#define COMPUTE(buf)                                                         \
  {                                                                          \
    const unsigned char* Lc = &lds[buf][0];                                  \
    i32x8 a_[2], b_[2];                                                      \
    _Pragma("unroll")                                                        \
    for (int m = 0; m < 2; ++m) {                                            \
      i32x4 lo = *(const i32x4*)(Lc + (wr * 2 + m) * 2048 + l16);            \
      i32x4 hi = *(const i32x4*)(Lc + (wr * 2 + m) * 2048 + 1024 + l16);     \
      a_[m] = __builtin_shufflevector(lo, hi, 0, 1, 2, 3, 4, 5, 6, 7);       \
    }                                                                        \
    _Pragma("unroll")                                                        \
    for (int n = 0; n < 2; ++n) {                                            \
      i32x4 lo = *(const i32x4*)(Lc + 16384 + (wc * 2 + n) * 2048 + l16);    \
      i32x4 hi = *(const i32x4*)(Lc + 16384 + (wc * 2 + n) * 2048 + 1024 + l16); \
      b_[n] = __builtin_shufflevector(lo, hi, 0, 1, 2, 3, 4, 5, 6, 7);       \
    }                                                                        \
    _Pragma("unroll")                                                        \
    for (int m = 0; m < 2; ++m)                                              \
      _Pragma("unroll")                                                      \
      for (int n = 0; n < 2; ++n)                                            \
        acc[m][n] = __builtin_amdgcn_mfma_scale_f32_32x32x64_f8f6f4(         \
            a_[m], b_[n], acc[m][n], 0, 0, 0, 0x7F7F7F7F, 0, 0x7F7F7F7F);    \
  }

  // prologue: chunk 0 in flight (3 loads/wave)
  STAGE(0, 0)

  // main loop: after STAGE, FIFO = {kc:3, kc+1:3}; vmcnt(3) retires chunk
  // kc, leaves kc+1 in flight across both barriers.
#pragma unroll 1
  for (int kt = 0; kt < 15; ++kt) {
    STAGE(kt + 1, (kt + 1) & 1)
    asm volatile("s_waitcnt vmcnt(3)" ::: "memory");
    __builtin_amdgcn_s_barrier();
    COMPUTE(kt & 1)
    __builtin_amdgcn_s_barrier();
  }
  asm volatile("s_waitcnt vmcnt(0)" ::: "memory");
  __builtin_amdgcn_s_barrier();
  COMPUTE(1)
#undef COMPUTE
#undef STAGE

  // epilogue: exp (fixed-max LSE; |logit| <= 10, no overflow possible)
#pragma unroll
  for (int m = 0; m < 2; ++m)
#pragma unroll
    for (int n = 0; n < 2; ++n)
#pragma unroll
      for (int r = 0; r < 16; ++r)
        acc[m][n][r] = __expf(acc[m][n][r] * EPILOGUE_SCALE);

  // 32x32 C/D layout: col = lane&31, row = (reg&3)+8*(reg>>2)+4*(lane>>5)
  // [measured m74/m101]
  const int rowBase = rowT * 256 + wr * 64;
  const int colBase = colT * 128 + wc * 64;
#pragma unroll
  for (int m = 0; m < 2; ++m) {
    f32x16 s = acc[m][0] + acc[m][1];  // cols sum elementwise across n-tiles
#pragma unroll
    for (int r = 0; r < 16; ++r) {
      float v = s[r];
      v += __shfl_xor(v, 1, 64);
      v += __shfl_xor(v, 2, 64);
      v += __shfl_xor(v, 4, 64);
      v += __shfl_xor(v, 8, 64);
      v += __shfl_xor(v, 16, 64);
      if ((l & 31) == 0)
        atomicAdd(&rowsum[rowBase + m * 32 + (r & 3) + 8 * (r >> 2) + 4 * (l >> 5)], v);
    }
  }
#pragma unroll
  for (int n = 0; n < 2; ++n) {
    float v = 0.f;
#pragma unroll
    for (int r = 0; r < 16; ++r) v += acc[0][n][r] + acc[1][n][r];
    v += __shfl_xor(v, 32, 64);  // combine the two row-half lane groups
    if (l < 32)
      atomicAdd(&colsum[colBase + n * 32 + l], v);
  }
}

// Kernel 3: scalar reduce. [unchanged]
__global__ __launch_bounds__(256) void finalize_k(
    const float* __restrict__ rowsum, const float* __restrict__ colsum,
    const float* __restrict__ diag, float* __restrict__ out) {
  const int t = threadIdx.x;
  float lse = 0.f, dg = 0.f;
  for (int i = t; i < N_; i += 256) {
    lse += __logf(rowsum[i]) + __logf(colsum[i]);
    dg += diag[i];
  }
#pragma unroll
  for (int o = 32; o > 0; o >>= 1) {
    lse += __shfl_down(lse, o, 64);
    dg  += __shfl_down(dg, o, 64);
  }
  __shared__ float red[2][4];
  const int w = t >> 6, l = t & 63;
  if (l == 0) { red[0][w] = lse; red[1][w] = dg; }
  __syncthreads();
  if (t == 0) {
    lse = red[0][0] + red[0][1] + red[0][2] + red[0][3];
    dg  = red[1][0] + red[1][1] + red[1][2] + red[1][3];
    out[0] = 0.5f * lse / (float)N_ - dg / (float)N_;
  }
}

extern "C" void kernel_launch(void* const* d_in, const int* in_sizes, int n_in,
                              void* d_out, int out_size, void* d_ws, size_t ws_size,
                              hipStream_t stream) {
  const float* im = (const float*)d_in[0];
  const float* cap = (const float*)d_in[1];
  float* out = (float*)d_out;
  char* ws = (char*)d_ws;
  unsigned char* imn = (unsigned char*)ws;                 // 8 MB fp8 (fragment layout)
  unsigned char* capn = imn + (size_t)N_ * D_;             // 8 MB fp8 (fragment layout)
  float* rowsum = (float*)(ws + 2 * (size_t)N_ * D_);
  float* colsum = rowsum + N_;
  float* diag = colsum + N_;

  normalize_k<<<512, 256, 0, stream>>>(im, cap, (unsigned int*)imn,
                                       (unsigned int*)capn, diag, rowsum);
  gemm_lse_k<<<dim3(32, 64), 512, 0, stream>>>(imn, capn, rowsum, colsum);
  finalize_k<<<1, 256, 0, stream>>>(rowsum, colsum, diag, out);
}